// Round 11
// baseline (493.097 us; speedup 1.0000x reference)
//
#include <hip/hip_runtime.h>

#define CUTOFF_F   0.1f
#define PRESSURE_F 10.0f

// Native clang vector type: __builtin_nontemporal_load requires a pointer to
// scalar/native-vector (HIP_vector_type<float,4> is rejected).
typedef float f32x4 __attribute__((ext_vector_type(4)));

__device__ __forceinline__ f32x4 ntload4(const float* p) {
    return __builtin_nontemporal_load(reinterpret_cast<const f32x4*>(p));
}

// Geometry: one row (256 fp32 = 1 KiB) = one wave (64 lanes x 16 B), fully
// coalesced. Unroll x4 rows -> 8 independent global_load_dwordx4(nt) in
// flight per iteration.
// Packed 4-row reduction (7 shuffles instead of 24):
//   stage m=1: lane l -> pair-sum over {l,l^1} of row (l&1)      (2 shuffles)
//   stage m=2: lane l -> quad-sum over {l..l^3} of row (l&3)     (1 shuffle)
//   stages m=4,8,16,32: full 64-lane sum of row (l&3)            (4 shuffles)
// Each row's penalty is then computed by 16 lanes; the 16x redundancy is
// folded into scale = 1/(16*B).
__global__ __launch_bounds__(256) void eucl_loss_kernel(
    const float* __restrict__ a,
    const float* __restrict__ b,
    float* __restrict__ out,
    int nRows,
    float scale)   // = 1/(16*B)
{
    __shared__ float wave_sums[4];

    const int lane   = threadIdx.x & 63;
    const int wave   = threadIdx.x >> 6;
    const int gwave  = blockIdx.x * 4 + wave;
    const int nwaves = gridDim.x * 4;          // 8192 at grid=2048

    const unsigned lane_e = (unsigned)lane * 4;
    const unsigned rowN   = (unsigned)nwaves * 256u;   // elem stride between unrolled rows

    const int step  = 4 * nwaves;
    const int nFull = nRows - (nRows % step);  // exact at B=262144: nFull == nRows

    float acc = 0.0f;

    for (int r0 = gwave; r0 < nFull; r0 += step) {
        const unsigned e0 = (unsigned)r0 * 256u + lane_e;

        // 8 independent 16B nt loads in flight
        const f32x4 va0 = ntload4(a + e0);
        const f32x4 vb0 = ntload4(b + e0);
        const f32x4 va1 = ntload4(a + e0 + rowN);
        const f32x4 vb1 = ntload4(b + e0 + rowN);
        const f32x4 va2 = ntload4(a + e0 + 2 * rowN);
        const f32x4 vb2 = ntload4(b + e0 + 2 * rowN);
        const f32x4 va3 = ntload4(a + e0 + 3 * rowN);
        const f32x4 vb3 = ntload4(b + e0 + 3 * rowN);

#define SSQ(VA, VB)                                                          \
        ({ const float dx = (VA).x - (VB).x;                                 \
           const float dy = (VA).y - (VB).y;                                 \
           const float dz = (VA).z - (VB).z;                                 \
           const float dw = (VA).w - (VB).w;                                 \
           dx * dx + dy * dy + dz * dz + dw * dw; })

        const float s0 = SSQ(va0, vb0);
        const float s1 = SSQ(va1, vb1);
        const float s2 = SSQ(va2, vb2);
        const float s3 = SSQ(va3, vb3);
#undef SSQ

        // --- packed 4-row butterfly (7 shuffles) ---
        // stage mask=1
        float x = (lane & 1) ? s1 : s0;        // own partial of row (lane&1)
        float y = (lane & 1) ? s0 : s1;        // partner's row
        x += __shfl_xor(y, 1, 64);
        float u = (lane & 1) ? s3 : s2;        // own partial of row 2+(lane&1)
        float v = (lane & 1) ? s2 : s3;
        u += __shfl_xor(v, 1, 64);
        // stage mask=2
        float p = (lane & 2) ? u : x;          // row (lane&3)
        float q = (lane & 2) ? x : u;
        p += __shfl_xor(q, 2, 64);
        // shared stages: all 4 rows reduced simultaneously
        p += __shfl_xor(p, 4, 64);
        p += __shfl_xor(p, 8, 64);
        p += __shfl_xor(p, 16, 64);
        p += __shfl_xor(p, 32, 64);

        const float dev = sqrtf(p) - CUTOFF_F;
        const float mlt = (dev > 0.0f) ? 1.0f : PRESSURE_F;
        acc += dev * dev * mlt;                // row (lane&3), counted 16x
    }

    // Tail (never taken at B=262144, grid=2048; kept for generality).
    for (int r = nFull + gwave; r < nRows; r += nwaves) {
        const unsigned e = (unsigned)r * 256u + lane_e;
        const f32x4 va = ntload4(a + e);
        const f32x4 vb = ntload4(b + e);
        const float dx = va.x - vb.x, dy = va.y - vb.y;
        const float dz = va.z - vb.z, dw = va.w - vb.w;
        float s = dx * dx + dy * dy + dz * dz + dw * dw;
        s += __shfl_xor(s, 32, 64);
        s += __shfl_xor(s, 16, 64);
        s += __shfl_xor(s, 8, 64);
        s += __shfl_xor(s, 4, 64);
        s += __shfl_xor(s, 2, 64);
        s += __shfl_xor(s, 1, 64);
        const float dev = sqrtf(s) - CUTOFF_F;
        const float mlt = (dev > 0.0f) ? 1.0f : PRESSURE_F;
        if ((lane & 3) == 0) acc += dev * dev * mlt;   // 16 lanes -> 16x, matches scale
    }

    // acc varies per lane: one full wave reduction outside the hot loop.
    acc += __shfl_xor(acc, 32, 64);
    acc += __shfl_xor(acc, 16, 64);
    acc += __shfl_xor(acc, 8, 64);
    acc += __shfl_xor(acc, 4, 64);
    acc += __shfl_xor(acc, 2, 64);
    acc += __shfl_xor(acc, 1, 64);

    if (lane == 0) wave_sums[wave] = acc;
    __syncthreads();

    if (threadIdx.x == 0) {
        const float t = (wave_sums[0] + wave_sums[1]) + (wave_sums[2] + wave_sums[3]);
        atomicAdd(out, t * scale);
    }
}

extern "C" void kernel_launch(void* const* d_in, const int* in_sizes, int n_in,
                              void* d_out, int out_size, void* d_ws, size_t ws_size,
                              hipStream_t stream) {
    const float* a = (const float*)d_in[0];
    const float* b = (const float*)d_in[1];
    float* out = (float*)d_out;

    const int D = 256;
    const int B = in_sizes[0] / D;        // 262144 rows

    // d_out re-poisoned to 0xAA before every timed call — zero it async.
    (void)hipMemsetAsync(out, 0, sizeof(float), stream);

    const int block = 256;                // 4 waves
    const int grid  = 2048;               // 8 blocks/CU x 256 CU
    const float scale = 1.0f / (16.0f * (float)B);
    eucl_loss_kernel<<<grid, block, 0, stream>>>(a, b, out, B, scale);
}